// Round 14
// baseline (182.730 us; speedup 1.0000x reference)
//
#include <hip/hip_runtime.h>
#include <math.h>

#define NELEC 10
#define NSPIN 2
#define NPER 5
#define DIM 3
#define NION 2
#define DP 32
#define NDENSE 64
#define NPERM 120
#define RS 324    // G row stride (words). Stage-A G rows per spin start at banks {0,4,..,16}
                  // (spin0) / {20,24,28,0,4} (spin1) -> 5 disjoint bank-quads per wave. 0 conflicts R5-R13.
#define SAW 1780  // stage-A words per spin: s1e[160] + 5*324
#define HT2S 248  // shared HT row stride (words): spin s at column offset 124*s (124%4==0, b128 ok).
                  // Per-wave reads: 8 distinct b128 addrs spanning 64 consecutive words -> 2 addrs
                  // per bank-quad (free, m136). Writes lane-consecutive b32 -> 2 lanes/bank (free).
#define HTK 32    // HT holds 32 k-rows at a time (k-split; phase 2 runs in two halves)

// Shared LDS pool with live-range overlay:
//   stage A (stages 1-2 + phase-1 G reads): s1e/G for both spins @ [0, 2*SAW)
//   stage B (phase 2): HT32[32][248] @ [0, 7936)  -- holds h[k-half] for BOTH spins
// h is carried in REGISTERS across the A->B transition and across the half-boundary.
// Pool = 31744 B (vs R13's 64000) -> LDS no longer the residency cap.
#define POOL_WORDS (HTK * HT2S)

typedef float v2f __attribute__((ext_vector_type(2)));
typedef float v4f __attribute__((ext_vector_type(4)));

// Packed fp32 FMA (VOP3P), bit-identical to scalar v_fma pairs (R12-validated).
#define PK_FMA_LO(acc, hp, wp) \
    asm("v_pk_fma_f32 %0, %1, %2, %0 op_sel_hi:[1,0,1]" : "+v"(acc) : "v"(hp), "v"(wp))
#define PK_FMA_HI(acc, hp, wp) \
    asm("v_pk_fma_f32 %0, %1, %2, %0 op_sel:[0,1,0] op_sel_hi:[1,1,1]" : "+v"(acc) : "v"(hp), "v"(wp))

// tanh(x) = 1 - 2*rcp(exp(2x)+1): ~1-2 ulp, exact at saturation. Validated R5-R13.
__device__ __forceinline__ float fast_tanh(float x) {
    float e = __expf(2.0f * x);
    return 1.0f - 2.0f * __builtin_amdgcn_rcpf(e + 1.0f);
}

__device__ __forceinline__ unsigned pick_remove(unsigned& el, int d) {
    unsigned v = (el >> (4 * d)) & 0xFu;
    unsigned low = el & ((1u << (4 * d)) - 1u);
    el = low | ((el >> (4 * (d + 1))) << (4 * d));
    return v;
}

// ---------------- fused: one block per batch element, 4 waves = 2 spin-pairs ----------------
// R13 validated the fused structure (100us dispatch, prediction matched). This round:
// k-split HT overlay halves LDS (64000 -> ~32000 B) so residency rises 8 -> 12 waves/CU
// (VGPR ~140 caps 3 waves/SIMD). Phase 2 = two 32-k GEMM halves; h[32:64] held in regs
// and re-staged into the shared HT between halves. Everything else R13-identical.
__global__ __launch_bounds__(256, 1) void antisym_fused(
    const float* __restrict__ elec_pos, const float* __restrict__ ion_pos,
    const float* __restrict__ bf_w, const float* __restrict__ bf_b,
    const float* __restrict__ w0, const float* __restrict__ b0,
    const float* __restrict__ w1, const float* __restrict__ b1,
    const float* __restrict__ w2, const float* __restrict__ jk,
    float* __restrict__ out, int B)
{
    const int b = blockIdx.x;
    const int t = threadIdx.x;
    const int s = t >> 7;                   // spin: waves 0-1 -> 0, waves 2-3 -> 1
    const int ts = t & 127;                 // thread within the spin-pair
    const int wave = (t >> 6) & 1;          // wave within the spin-pair
    const int lane = t & 63;

    __shared__ __align__(16) float pool[POOL_WORDS];    // 31744 B, overlaid (see above)
    __shared__ double red_h[NSPIN][2];
    __shared__ double red_j[NSPIN][2];
    __shared__ float jterm[2 * NELEC];

    float* s1e = pool + s * SAW;                              // [160]    (stage A)
    #define GROW(j) (pool + s * SAW + 160 + (j) * RS)         // G[j][.]  (stage A)
    #define HT32(k) (pool + (k) * HT2S)                       // HT row k (stage B, shared)

    // ---- stage 1: stream_1e = tanh(feats @ bf_w + bf_b), this spin's 5 electrons ----
    const float* ep = elec_pos + (b * NELEC + s * NPER) * DIM;
    const float i0x = ion_pos[0], i0y = ion_pos[1], i0z = ion_pos[2];
    const float i1x = ion_pos[3], i1y = ion_pos[4], i1z = ion_pos[5];
    for (int idx = ts; idx < NPER * DP; idx += 128) {
        int j = idx >> 5, c = idx & 31;
        float ex = ep[j * 3 + 0], ey = ep[j * 3 + 1], ez = ep[j * 3 + 2];
        float dx0 = ex - i0x, dy0 = ey - i0y, dz0 = ez - i0z;
        float dx1 = ex - i1x, dy1 = ey - i1y, dz1 = ez - i1z;
        float n0 = sqrtf(dx0 * dx0 + dy0 * dy0 + dz0 * dz0);
        float n1 = sqrtf(dx1 * dx1 + dy1 * dy1 + dz1 * dz1);
        float acc = bf_b[c];
        acc += dx0 * bf_w[0 * DP + c];
        acc += dy0 * bf_w[1 * DP + c];
        acc += dz0 * bf_w[2 * DP + c];
        acc += dx1 * bf_w[3 * DP + c];
        acc += dy1 * bf_w[4 * DP + c];
        acc += dz1 * bf_w[5 * DP + c];
        acc += n0 * bf_w[6 * DP + c];
        acc += n1 * bf_w[7 * DP + c];
        s1e[idx] = fast_tanh(acc);
    }
    // jastrow terms (combine's exact per-term math; summed e-major by t0 later)
    if (t < 2 * NELEC) {
        int e = t >> 1, ion = t & 1;
        const float* epb = elec_pos + b * NELEC * DIM;
        float ex = epb[e * 3 + 0], ey = epb[e * 3 + 1], ez = epb[e * 3 + 2];
        float ix = ion_pos[ion * 3 + 0], iy = ion_pos[ion * 3 + 1], iz = ion_pos[ion * 3 + 2];
        float dx = ex - ix, dy = ey - iy, dz = ez - iz;
        jterm[t] = jk[ion] * sqrtf(dx * dx + dy * dy + dz * dz);
    }
    __syncthreads();

    // ---- stage 2: G[j][i*64+c] = s1e[j][:] @ w0[s][32i:32i+32, c] (R5-R13 validated) ----
    const float* w0s = w0 + s * (NPER * DP) * NDENSE;   // [160][64]
    for (int j = wave; j < NPER; j += 2) {
        float4 sv4[8];
        #pragma unroll
        for (int q = 0; q < 8; q++) sv4[q] = *(const float4*)(s1e + j * DP + q * 4);
        #pragma unroll
        for (int i = 0; i < NPER; i++) {
            float acc = 0.f;
            #pragma unroll
            for (int q = 0; q < 8; q++) {
                const float* wb = w0s + (i * DP + q * 4) * NDENSE + lane;  // coalesced
                acc += sv4[q].x * wb[0 * NDENSE];
                acc += sv4[q].y * wb[1 * NDENSE];
                acc += sv4[q].z * wb[2 * NDENSE];
                acc += sv4[q].w * wb[3 * NDENSE];
            }
            GROW(j)[i * NDENSE + lane] = acc;
        }
    }
    __syncthreads();

    const float* b0s = b0 + s * NDENSE;
    const float* w2s = w2 + s * NDENSE;     // w2 is [s][64][1]

    // ---- stage 3 phase 1: lane = perm. h_p built in registers (G still live) ----
    const int pid = wave * 60 + lane;
    float sign = 0.f;
    int p0 = 0, p1 = 0, p2 = 0, p3 = 0, p4 = 0;
    if (lane < 60) {
        int p = pid;
        unsigned el = 0x43210u;
        int d0 = p / 24; p -= d0 * 24;
        int d1 = p / 6;  p -= d1 * 6;
        int d2 = p / 2;  p -= d2 * 2;
        int d3 = p;
        p0 = pick_remove(el, d0);
        p1 = pick_remove(el, d1);
        p2 = pick_remove(el, d2);
        p3 = pick_remove(el, d3);
        p4 = el & 0xF;
        sign = ((d0 + d1 + d2 + d3) & 1) ? -1.f : 1.f;
    }
    const float* g0 = GROW(p0) + 0 * NDENSE;
    const float* g1 = GROW(p1) + 1 * NDENSE;
    const float* g2 = GROW(p2) + 2 * NDENSE;
    const float* g3 = GROW(p3) + 3 * NDENSE;
    const float* g4 = GROW(p4) + 4 * NDENSE;

    float h[NDENSE];                        // constant-indexed -> VGPR-resident
    float hdot = 0.f;
    #pragma unroll
    for (int cc = 0; cc < NDENSE / 4; cc++) {
        float4 a = *(const float4*)(b0s + cc * 4);                    // uniform -> s_load
        float4 q;
        q = *(const float4*)(g0 + cc * 4); a.x += q.x; a.y += q.y; a.z += q.z; a.w += q.w;
        q = *(const float4*)(g1 + cc * 4); a.x += q.x; a.y += q.y; a.z += q.z; a.w += q.w;
        q = *(const float4*)(g2 + cc * 4); a.x += q.x; a.y += q.y; a.z += q.z; a.w += q.w;
        q = *(const float4*)(g3 + cc * 4); a.x += q.x; a.y += q.y; a.z += q.z; a.w += q.w;
        q = *(const float4*)(g4 + cc * 4); a.x += q.x; a.y += q.y; a.z += q.z; a.w += q.w;
        float t0 = fast_tanh(a.x), t1 = fast_tanh(a.y), t2 = fast_tanh(a.z), t3 = fast_tanh(a.w);
        h[cc * 4 + 0] = t0; h[cc * 4 + 1] = t1; h[cc * 4 + 2] = t2; h[cc * 4 + 3] = t3;
        hdot += t0 * w2s[cc * 4 + 0] + t1 * w2s[cc * 4 + 1]
              + t2 * w2s[cc * 4 + 2] + t3 * w2s[cc * 4 + 3];
    }

    double dvh = (double)(sign * hdot);     // sign=0 for lanes 60-63
    #pragma unroll
    for (int off = 32; off > 0; off >>= 1) dvh += __shfl_down(dvh, off, 64);
    if (lane == 0) red_h[s][wave] = dvh;

    __syncthreads();                        // all G reads complete -> pool reusable

    // ---- stage 3 phase 2: 8x8 tile GEMM V[120x64] = H @ W1 in TWO 32-k halves ----
    const int pg = lane >> 3, jg = lane & 7;
    const int pbl = wave ? (56 + 8 * pg) : (8 * pg);     // perm base (logical)
    const int pb = pbl + 124 * s;                        // + spin column offset in shared HT
    const float* w1s = w1 + s * NDENSE * NDENSE;
    const float* b1s = b1 + s * NDENSE;
    const float* wgp = w1s + 8 * jg;        // this lane's j-octet in w1 row k

    v2f vp[4][8];
    #pragma unroll
    for (int ip = 0; ip < 4; ip++)
        #pragma unroll
        for (int r = 0; r < 8; r++) vp[ip][r] = (v2f)(0.f);

    #pragma unroll 1
    for (int half = 0; half < 2; half++) {
        // stage this half's h k-rows into the shared HT (both spins write their columns)
        if (lane < 60) {
            #pragma unroll
            for (int kk = 0; kk < HTK; kk++)
                HT32(kk)[124 * s + pid] = h[half * HTK + kk];
        }
        __syncthreads();                     // HT visible to both waves of this spin

        const float* wh = wgp + half * HTK * NDENSE;
        v4f ha_n = *(const v4f*)(&HT32(0)[pb]);
        v4f hb_n = *(const v4f*)(&HT32(0)[pb + 4]);
        v4f wa_n = *(const v4f*)(wh);
        v4f wb_n = *(const v4f*)(wh + 4);
        #pragma unroll 4
        for (int kk = 0; kk < HTK; kk++) {
            const v4f ha = ha_n, hb = hb_n, wa = wa_n, wb = wb_n;
            if (kk + 1 < HTK) {              // R10-validated k+1 prefetch
                ha_n = *(const v4f*)(&HT32(kk + 1)[pb]);
                hb_n = *(const v4f*)(&HT32(kk + 1)[pb + 4]);
                wa_n = *(const v4f*)(wh + (kk + 1) * NDENSE);
                wb_n = *(const v4f*)(wh + (kk + 1) * NDENSE + 4);
            }
            v2f hp[4] = {ha.xy, ha.zw, hb.xy, hb.zw};   // perm pairs
            v2f wp[4] = {wa.xy, wa.zw, wb.xy, wb.zw};   // j pairs
            #pragma unroll
            for (int ip = 0; ip < 4; ip++) {
                PK_FMA_LO(vp[ip][0], hp[ip], wp[0]);
                PK_FMA_HI(vp[ip][1], hp[ip], wp[0]);
                PK_FMA_LO(vp[ip][2], hp[ip], wp[1]);
                PK_FMA_HI(vp[ip][3], hp[ip], wp[1]);
                PK_FMA_LO(vp[ip][4], hp[ip], wp[2]);
                PK_FMA_HI(vp[ip][5], hp[ip], wp[2]);
                PK_FMA_LO(vp[ip][6], hp[ip], wp[3]);
                PK_FMA_HI(vp[ip][7], hp[ip], wp[3]);
            }
        }
        if (half == 0) __syncthreads();      // all reads of half-0 HT done before overwrite
    }

    // epilogue: lanesum = sum_i sgn_i * sum_r tanh(v[i][r]+b1[j]) * w2[j]
    float4 b1a = *(const float4*)(b1s + 8 * jg);
    float4 b1b = *(const float4*)(b1s + 8 * jg + 4);
    float4 w2a = *(const float4*)(w2s + 8 * jg);
    float4 w2b = *(const float4*)(w2s + 8 * jg + 4);
    const float b1v[8] = {b1a.x, b1a.y, b1a.z, b1a.w, b1b.x, b1b.y, b1b.z, b1b.w};
    const float w2v[8] = {w2a.x, w2a.y, w2a.z, w2a.w, w2b.x, w2b.y, w2b.z, w2b.w};

    float lanesum = 0.f;
    #pragma unroll
    for (int i = 0; i < 8; i++) {
        int p = pbl + i;                     // Lehmer parity
        int d0 = p / 24;  int r0 = p - 24 * d0;
        int d1 = r0 / 6;  int r1 = r0 - 6 * d1;
        int d2 = r1 >> 1; int d3 = r1 & 1;
        float sgn = ((d0 + d1 + d2 + d3) & 1) ? -1.f : 1.f;
        if (wave == 1 && pg == 0) sgn = 0.f; // duplicate tile (perms 56-63)
        float si = 0.f;
        #pragma unroll
        for (int r = 0; r < 8; r++) {
            float vir = (i & 1) ? vp[i >> 1][r].y : vp[i >> 1][r].x;
            si = fmaf(fast_tanh(vir + b1v[r]), w2v[r], si);
        }
        lanesum = fmaf(sgn, si, lanesum);
    }

    double dvj = (double)lanesum;
    #pragma unroll
    for (int off = 32; off > 0; off >>= 1) dvj += __shfl_down(dvj, off, 64);
    if (lane == 0) red_j[s][wave] = dvj;
    __syncthreads();

    // ---- inline combine (R13-validated) ----
    if (t == 0) {
        float ps0 = (float)((red_h[0][0] + red_h[0][1]) + (red_j[0][0] + red_j[0][1]));
        float ps1 = (float)((red_h[1][0] + red_h[1][1]) + (red_j[1][0] + red_j[1][1]));
        float jas = 0.f;
        #pragma unroll
        for (int i = 0; i < 2 * NELEC; i++) jas += jterm[i];
        out[b] = logf(fabsf(ps0 * ps1)) - jas;
    }
    // b2 omitted: sum_p sign_p = 0 kills it exactly.
}

extern "C" void kernel_launch(void* const* d_in, const int* in_sizes, int n_in,
                              void* d_out, int out_size, void* d_ws, size_t ws_size,
                              hipStream_t stream) {
    const float* elec_pos = (const float*)d_in[0];
    const float* ion_pos  = (const float*)d_in[1];
    const float* bf_w     = (const float*)d_in[2];
    const float* bf_b     = (const float*)d_in[3];
    const float* w0       = (const float*)d_in[4];
    const float* b0       = (const float*)d_in[5];
    const float* w1       = (const float*)d_in[6];
    const float* b1       = (const float*)d_in[7];
    const float* w2       = (const float*)d_in[8];
    const float* jk       = (const float*)d_in[10];
    float* out = (float*)d_out;

    const int B = in_sizes[0] / (NELEC * DIM);   // 2048

    hipLaunchKernelGGL(antisym_fused,
                       dim3(B), dim3(256), 0, stream,
                       elec_pos, ion_pos, bf_w, bf_b, w0, b0, w1, b1, w2, jk, out, B);
}

// Round 15
// 158.892 us; speedup vs baseline: 1.1500x; 1.1500x over previous
//
#include <hip/hip_runtime.h>
#include <math.h>

#define NELEC 10
#define NSPIN 2
#define NPER 5
#define DIM 3
#define NION 2
#define DP 32
#define NDENSE 64
#define NPERM 120
#define RS 324    // G row stride (words). Base 320 + s*1620 + j*324: row-start banks
                  // {0,4,8,12,16} (s=0) / {20,24,28,0,4} (s=1) -> 5 disjoint quads per wave.
                  // 1620 = 20 mod 32 == validated R13 layout (1780 = 20 mod 32). 0 conflicts R5-R13.
#define HT2S 248  // shared HT row stride (words): spin s at column offset 124*s. Per-wave b128
                  // reads: 8 addrs spanning 64 words -> 2/bank-quad (free, m136). Writes
                  // lane-consecutive b32 -> 2 lanes/bank (free). All offsets %4==0 -> b128 ok.
#define HTK 32    // HT holds 32 k-rows (k-split; phase 2 = two 32-k GEMM halves)
#define HTBASE 3560                    // 320 (s1e x2) + 3240 (G x2)
#define POOL_WORDS (HTBASE + HTK * HT2S)   // 11496 words = 45984 B

// LDS layout (NO overlay this round -- G stays live through phase 2):
//   s1e[2][160] @ [0,320) ; G[2][5][324] @ [320,3560) ; HT32[32][248] @ [3560,11496)
// h is computed in 32-element halves INSIDE a fully-unrolled loop (constant indexing --
// R14's 131MB scratch disaster was `h[half*32+kk]` with dynamic `half`). 46 KB LDS ->
// 3 blocks/CU = 12 waves/CU (+50% vs R13's 8): the clean occupancy experiment.

typedef float v2f __attribute__((ext_vector_type(2)));
typedef float v4f __attribute__((ext_vector_type(4)));

// Packed fp32 FMA (VOP3P), bit-identical to scalar v_fma pairs (R12/R13-validated).
#define PK_FMA_LO(acc, hp, wp) \
    asm("v_pk_fma_f32 %0, %1, %2, %0 op_sel_hi:[1,0,1]" : "+v"(acc) : "v"(hp), "v"(wp))
#define PK_FMA_HI(acc, hp, wp) \
    asm("v_pk_fma_f32 %0, %1, %2, %0 op_sel:[0,1,0] op_sel_hi:[1,1,1]" : "+v"(acc) : "v"(hp), "v"(wp))

// tanh(x) = 1 - 2*rcp(exp(2x)+1): ~1-2 ulp, exact at saturation. Validated R5-R13.
__device__ __forceinline__ float fast_tanh(float x) {
    float e = __expf(2.0f * x);
    return 1.0f - 2.0f * __builtin_amdgcn_rcpf(e + 1.0f);
}

__device__ __forceinline__ unsigned pick_remove(unsigned& el, int d) {
    unsigned v = (el >> (4 * d)) & 0xFu;
    unsigned low = el & ((1u << (4 * d)) - 1u);
    el = low | ((el >> (4 * (d + 1))) << (4 * d));
    return v;
}

// ---------------- fused: one block per batch element, 4 waves = 2 spin-pairs ----------------
__global__ __launch_bounds__(256, 1) void antisym_fused(
    const float* __restrict__ elec_pos, const float* __restrict__ ion_pos,
    const float* __restrict__ bf_w, const float* __restrict__ bf_b,
    const float* __restrict__ w0, const float* __restrict__ b0,
    const float* __restrict__ w1, const float* __restrict__ b1,
    const float* __restrict__ w2, const float* __restrict__ jk,
    float* __restrict__ out, int B)
{
    const int b = blockIdx.x;
    const int t = threadIdx.x;
    const int s = t >> 7;                   // spin: waves 0-1 -> 0, waves 2-3 -> 1
    const int ts = t & 127;                 // thread within the spin-pair
    const int wave = (t >> 6) & 1;          // wave within the spin-pair
    const int lane = t & 63;

    __shared__ __align__(16) float pool[POOL_WORDS];    // 45984 B (see layout above)
    __shared__ double red_h[NSPIN][2];
    __shared__ double red_j[NSPIN][2];
    __shared__ float jterm[2 * NELEC];

    float* s1e = pool + s * 160;                              // stage A
    #define GROW(j) (pool + 320 + s * (NPER * RS) + (j) * RS) // G[s][j][.], live ALL phases
    #define HT32(k) (pool + HTBASE + (k) * HT2S)              // shared HT, stage B

    // ---- stage 1: stream_1e = tanh(feats @ bf_w + bf_b), this spin's 5 electrons ----
    const float* ep = elec_pos + (b * NELEC + s * NPER) * DIM;
    const float i0x = ion_pos[0], i0y = ion_pos[1], i0z = ion_pos[2];
    const float i1x = ion_pos[3], i1y = ion_pos[4], i1z = ion_pos[5];
    for (int idx = ts; idx < NPER * DP; idx += 128) {
        int j = idx >> 5, c = idx & 31;
        float ex = ep[j * 3 + 0], ey = ep[j * 3 + 1], ez = ep[j * 3 + 2];
        float dx0 = ex - i0x, dy0 = ey - i0y, dz0 = ez - i0z;
        float dx1 = ex - i1x, dy1 = ey - i1y, dz1 = ez - i1z;
        float n0 = sqrtf(dx0 * dx0 + dy0 * dy0 + dz0 * dz0);
        float n1 = sqrtf(dx1 * dx1 + dy1 * dy1 + dz1 * dz1);
        float acc = bf_b[c];
        acc += dx0 * bf_w[0 * DP + c];
        acc += dy0 * bf_w[1 * DP + c];
        acc += dz0 * bf_w[2 * DP + c];
        acc += dx1 * bf_w[3 * DP + c];
        acc += dy1 * bf_w[4 * DP + c];
        acc += dz1 * bf_w[5 * DP + c];
        acc += n0 * bf_w[6 * DP + c];
        acc += n1 * bf_w[7 * DP + c];
        s1e[idx] = fast_tanh(acc);
    }
    // jastrow terms (combine's exact per-term math; summed e-major by t0 later)
    if (t < 2 * NELEC) {
        int e = t >> 1, ion = t & 1;
        const float* epb = elec_pos + b * NELEC * DIM;
        float ex = epb[e * 3 + 0], ey = epb[e * 3 + 1], ez = epb[e * 3 + 2];
        float ix = ion_pos[ion * 3 + 0], iy = ion_pos[ion * 3 + 1], iz = ion_pos[ion * 3 + 2];
        float dx = ex - ix, dy = ey - iy, dz = ez - iz;
        jterm[t] = jk[ion] * sqrtf(dx * dx + dy * dy + dz * dz);
    }
    __syncthreads();

    // ---- stage 2: G[j][i*64+c] = s1e[j][:] @ w0[s][32i:32i+32, c] (R5-R13 validated) ----
    const float* w0s = w0 + s * (NPER * DP) * NDENSE;   // [160][64]
    for (int j = wave; j < NPER; j += 2) {
        float4 sv4[8];
        #pragma unroll
        for (int q = 0; q < 8; q++) sv4[q] = *(const float4*)(s1e + j * DP + q * 4);
        #pragma unroll
        for (int i = 0; i < NPER; i++) {
            float acc = 0.f;
            #pragma unroll
            for (int q = 0; q < 8; q++) {
                const float* wb = w0s + (i * DP + q * 4) * NDENSE + lane;  // coalesced
                acc += sv4[q].x * wb[0 * NDENSE];
                acc += sv4[q].y * wb[1 * NDENSE];
                acc += sv4[q].z * wb[2 * NDENSE];
                acc += sv4[q].w * wb[3 * NDENSE];
            }
            GROW(j)[i * NDENSE + lane] = acc;
        }
    }
    __syncthreads();

    const float* b0s = b0 + s * NDENSE;
    const float* w2s = w2 + s * NDENSE;     // w2 is [s][64][1]

    // ---- stage 3: perm decode (lane = perm for h-build) ----
    const int pid = wave * 60 + lane;
    float sign = 0.f;
    int p0 = 0, p1 = 0, p2 = 0, p3 = 0, p4 = 0;
    if (lane < 60) {
        int p = pid;
        unsigned el = 0x43210u;
        int d0 = p / 24; p -= d0 * 24;
        int d1 = p / 6;  p -= d1 * 6;
        int d2 = p / 2;  p -= d2 * 2;
        int d3 = p;
        p0 = pick_remove(el, d0);
        p1 = pick_remove(el, d1);
        p2 = pick_remove(el, d2);
        p3 = pick_remove(el, d3);
        p4 = el & 0xF;
        sign = ((d0 + d1 + d2 + d3) & 1) ? -1.f : 1.f;
    }
    const float* g0 = GROW(p0) + 0 * NDENSE;
    const float* g1 = GROW(p1) + 1 * NDENSE;
    const float* g2 = GROW(p2) + 2 * NDENSE;
    const float* g3 = GROW(p3) + 3 * NDENSE;
    const float* g4 = GROW(p4) + 4 * NDENSE;

    // phase-2 tiling (lane = 8 perms x 8 j)
    const int pg = lane >> 3, jg = lane & 7;
    const int pbl = wave ? (56 + 8 * pg) : (8 * pg);     // perm base (logical)
    const int pb = pbl + 124 * s;                        // + spin column offset in shared HT
    const float* w1s = w1 + s * NDENSE * NDENSE;
    const float* b1s = b1 + s * NDENSE;
    const float* wgp = w1s + 8 * jg;        // this lane's j-octet in w1 row k

    float hdot = 0.f;
    v2f vp[4][8];
    #pragma unroll
    for (int ip = 0; ip < 4; ip++)
        #pragma unroll
        for (int r = 0; r < 8; r++) vp[ip][r] = (v2f)(0.f);

    // ---- two k-halves: build hh[32] from G (still live) -> stage HT -> 32-k GEMM ----
    // FULLY unrolled so `half` is a compile-time constant (constant indexing everywhere;
    // R14's scratch blowup was dynamic indexing into h[]).
    #pragma unroll
    for (int half = 0; half < 2; half++) {
        float hh[HTK];                       // constant-indexed -> VGPRs; dies at staging
        #pragma unroll
        for (int cc = 0; cc < 8; cc++) {
            const int c4 = half * HTK + cc * 4;
            float4 a = *(const float4*)(b0s + c4);                    // uniform -> s_load
            float4 q;
            q = *(const float4*)(g0 + c4); a.x += q.x; a.y += q.y; a.z += q.z; a.w += q.w;
            q = *(const float4*)(g1 + c4); a.x += q.x; a.y += q.y; a.z += q.z; a.w += q.w;
            q = *(const float4*)(g2 + c4); a.x += q.x; a.y += q.y; a.z += q.z; a.w += q.w;
            q = *(const float4*)(g3 + c4); a.x += q.x; a.y += q.y; a.z += q.z; a.w += q.w;
            q = *(const float4*)(g4 + c4); a.x += q.x; a.y += q.y; a.z += q.z; a.w += q.w;
            float t0 = fast_tanh(a.x), t1 = fast_tanh(a.y), t2 = fast_tanh(a.z), t3 = fast_tanh(a.w);
            hh[cc * 4 + 0] = t0; hh[cc * 4 + 1] = t1; hh[cc * 4 + 2] = t2; hh[cc * 4 + 3] = t3;
            hdot += t0 * w2s[c4 + 0] + t1 * w2s[c4 + 1]
                  + t2 * w2s[c4 + 2] + t3 * w2s[c4 + 3];
        }
        // stage this half into the shared HT (b32, lane-consecutive -> conflict-free)
        if (lane < 60) {
            #pragma unroll
            for (int kk = 0; kk < HTK; kk++) HT32(kk)[124 * s + pid] = hh[kk];
        }
        __syncthreads();                     // HT visible to both waves of each spin

        const float* wh = wgp + half * HTK * NDENSE;
        v4f ha_n = *(const v4f*)(&HT32(0)[pb]);
        v4f hb_n = *(const v4f*)(&HT32(0)[pb + 4]);
        v4f wa_n = *(const v4f*)(wh);
        v4f wb_n = *(const v4f*)(wh + 4);
        #pragma unroll 4
        for (int kk = 0; kk < HTK; kk++) {
            const v4f ha = ha_n, hb = hb_n, wa = wa_n, wb = wb_n;
            if (kk + 1 < HTK) {              // R10-validated k+1 prefetch
                ha_n = *(const v4f*)(&HT32(kk + 1)[pb]);
                hb_n = *(const v4f*)(&HT32(kk + 1)[pb + 4]);
                wa_n = *(const v4f*)(wh + (kk + 1) * NDENSE);
                wb_n = *(const v4f*)(wh + (kk + 1) * NDENSE + 4);
            }
            v2f hp[4] = {ha.xy, ha.zw, hb.xy, hb.zw};   // perm pairs
            v2f wp[4] = {wa.xy, wa.zw, wb.xy, wb.zw};   // j pairs
            #pragma unroll
            for (int ip = 0; ip < 4; ip++) {
                PK_FMA_LO(vp[ip][0], hp[ip], wp[0]);
                PK_FMA_HI(vp[ip][1], hp[ip], wp[0]);
                PK_FMA_LO(vp[ip][2], hp[ip], wp[1]);
                PK_FMA_HI(vp[ip][3], hp[ip], wp[1]);
                PK_FMA_LO(vp[ip][4], hp[ip], wp[2]);
                PK_FMA_HI(vp[ip][5], hp[ip], wp[2]);
                PK_FMA_LO(vp[ip][6], hp[ip], wp[3]);
                PK_FMA_HI(vp[ip][7], hp[ip], wp[3]);
            }
        }
        if (half == 0) __syncthreads();      // all reads of half-0 HT done before overwrite
    }

    // sign*hdot reduction (order identical to R13: cc 0..15 accumulation)
    double dvh = (double)(sign * hdot);      // sign=0 for lanes 60-63
    #pragma unroll
    for (int off = 32; off > 0; off >>= 1) dvh += __shfl_down(dvh, off, 64);
    if (lane == 0) red_h[s][wave] = dvh;

    // epilogue: lanesum = sum_i sgn_i * sum_r tanh(v[i][r]+b1[j]) * w2[j]
    float4 b1a = *(const float4*)(b1s + 8 * jg);
    float4 b1b = *(const float4*)(b1s + 8 * jg + 4);
    float4 w2a = *(const float4*)(w2s + 8 * jg);
    float4 w2b = *(const float4*)(w2s + 8 * jg + 4);
    const float b1v[8] = {b1a.x, b1a.y, b1a.z, b1a.w, b1b.x, b1b.y, b1b.z, b1b.w};
    const float w2v[8] = {w2a.x, w2a.y, w2a.z, w2a.w, w2b.x, w2b.y, w2b.z, w2b.w};

    float lanesum = 0.f;
    #pragma unroll
    for (int i = 0; i < 8; i++) {
        int p = pbl + i;                     // Lehmer parity
        int d0 = p / 24;  int r0 = p - 24 * d0;
        int d1 = r0 / 6;  int r1 = r0 - 6 * d1;
        int d2 = r1 >> 1; int d3 = r1 & 1;
        float sgn = ((d0 + d1 + d2 + d3) & 1) ? -1.f : 1.f;
        if (wave == 1 && pg == 0) sgn = 0.f; // duplicate tile (perms 56-63)
        float si = 0.f;
        #pragma unroll
        for (int r = 0; r < 8; r++) {
            float vir = (i & 1) ? vp[i >> 1][r].y : vp[i >> 1][r].x;
            si = fmaf(fast_tanh(vir + b1v[r]), w2v[r], si);
        }
        lanesum = fmaf(sgn, si, lanesum);
    }

    double dvj = (double)lanesum;
    #pragma unroll
    for (int off = 32; off > 0; off >>= 1) dvj += __shfl_down(dvj, off, 64);
    if (lane == 0) red_j[s][wave] = dvj;
    __syncthreads();

    // ---- inline combine (R13-validated) ----
    if (t == 0) {
        float ps0 = (float)((red_h[0][0] + red_h[0][1]) + (red_j[0][0] + red_j[0][1]));
        float ps1 = (float)((red_h[1][0] + red_h[1][1]) + (red_j[1][0] + red_j[1][1]));
        float jas = 0.f;
        #pragma unroll
        for (int i = 0; i < 2 * NELEC; i++) jas += jterm[i];
        out[b] = logf(fabsf(ps0 * ps1)) - jas;
    }
    // b2 omitted: sum_p sign_p = 0 kills it exactly.
}

extern "C" void kernel_launch(void* const* d_in, const int* in_sizes, int n_in,
                              void* d_out, int out_size, void* d_ws, size_t ws_size,
                              hipStream_t stream) {
    const float* elec_pos = (const float*)d_in[0];
    const float* ion_pos  = (const float*)d_in[1];
    const float* bf_w     = (const float*)d_in[2];
    const float* bf_b     = (const float*)d_in[3];
    const float* w0       = (const float*)d_in[4];
    const float* b0       = (const float*)d_in[5];
    const float* w1       = (const float*)d_in[6];
    const float* b1       = (const float*)d_in[7];
    const float* w2       = (const float*)d_in[8];
    const float* jk       = (const float*)d_in[10];
    float* out = (float*)d_out;

    const int B = in_sizes[0] / (NELEC * DIM);   // 2048

    hipLaunchKernelGGL(antisym_fused,
                       dim3(B), dim3(256), 0, stream,
                       elec_pos, ion_pos, bf_w, bf_b, w0, b0, w1, b1, w2, jk, out, B);
}

// Round 16
// 155.119 us; speedup vs baseline: 1.1780x; 1.0243x over previous
//
#include <hip/hip_runtime.h>
#include <math.h>

#define NELEC 10
#define NSPIN 2
#define NPER 5
#define DIM 3
#define NION 2
#define DP 32
#define NDENSE 64
#define NPERM 120
#define RS 324   // G row stride (words): the 5 selectable rows land on disjoint bank quads.
#define HTS 124  // HT row stride (words): reads 2 addrs/bank-quad (free, m136); writes 2/bank free.

// Per-spin LDS pool with live-range overlay (R10/R12/R13-validated):
//   stage A: s1e[160] @ 0, G[5][324] @ 160..1780
//   stage B: HT[64][124] @ 0..7936
#define POOL_WORDS (NDENSE * HTS)

typedef float v2f __attribute__((ext_vector_type(2)));
typedef float v4f __attribute__((ext_vector_type(4)));

// Packed fp32 FMA (VOP3P), bit-identical to scalar v_fma pairs (R12-validated).
#define PK_FMA_LO(acc, hp, wp) \
    asm("v_pk_fma_f32 %0, %1, %2, %0 op_sel_hi:[1,0,1]" : "+v"(acc) : "v"(hp), "v"(wp))
#define PK_FMA_HI(acc, hp, wp) \
    asm("v_pk_fma_f32 %0, %1, %2, %0 op_sel:[0,1,0] op_sel_hi:[1,1,1]" : "+v"(acc) : "v"(hp), "v"(wp))

// tanh(x) = 1 - 2*rcp(exp(2x)+1): ~1-2 ulp, exact at saturation. Validated R5-R15.
__device__ __forceinline__ float fast_tanh(float x) {
    float e = __expf(2.0f * x);
    return 1.0f - 2.0f * __builtin_amdgcn_rcpf(e + 1.0f);
}

__device__ __forceinline__ unsigned pick_remove(unsigned& el, int d) {
    unsigned v = (el >> (4 * d)) & 0xFu;
    unsigned low = el & ((1u << (4 * d)) - 1u);
    el = low | ((el >> (4 * (d + 1))) << (4 * d));
    return v;
}

// ---------------- fused: one block per batch element, 4 waves = 2 spin-pairs ----------------
// Base = R13 (100us, best measured; R15's k-split occupancy experiment was a clean null
// and is reverted). ONE change vs R13: stage 2 restructured slice-outer with wcol[32]
// in registers -- 480 global loads/wave -> 96 (the worst load:FMA ratio in the kernel).
// Per-element arithmetic order bit-identical. (R3/R4's tripwire ghost was uninitialized
// LDS reads at t>=120 in the old hl design -- wcol itself was innocent; no uninit reads here.)
__global__ __launch_bounds__(256, 1) void antisym_fused(
    const float* __restrict__ elec_pos, const float* __restrict__ ion_pos,
    const float* __restrict__ bf_w, const float* __restrict__ bf_b,
    const float* __restrict__ w0, const float* __restrict__ b0,
    const float* __restrict__ w1, const float* __restrict__ b1,
    const float* __restrict__ w2, const float* __restrict__ jk,
    float* __restrict__ out, int B)
{
    const int b = blockIdx.x;
    const int t = threadIdx.x;
    const int s = t >> 7;                   // spin: waves 0-1 -> 0, waves 2-3 -> 1
    const int ts = t & 127;                 // thread within the spin-pair
    const int wave = (t >> 6) & 1;          // wave within the spin-pair
    const int lane = t & 63;

    __shared__ __align__(16) float pool[NSPIN][POOL_WORDS];   // 2 x 31744 B
    __shared__ double red_h[NSPIN][2];
    __shared__ double red_j[NSPIN][2];
    __shared__ float jterm[2 * NELEC];

    float* s1e = pool[s];                                     // [160]    (stage A)
    #define GROW(j) (pool[s] + 160 + (j) * RS)                // G[j][.]  (stage A)
    #define HTROW(k) (pool[s] + (k) * HTS)                    // HT[k][.] (stage B)

    // ---- stage 1: stream_1e = tanh(feats @ bf_w + bf_b), this spin's 5 electrons ----
    const float* ep = elec_pos + (b * NELEC + s * NPER) * DIM;
    const float i0x = ion_pos[0], i0y = ion_pos[1], i0z = ion_pos[2];
    const float i1x = ion_pos[3], i1y = ion_pos[4], i1z = ion_pos[5];
    for (int idx = ts; idx < NPER * DP; idx += 128) {
        int j = idx >> 5, c = idx & 31;
        float ex = ep[j * 3 + 0], ey = ep[j * 3 + 1], ez = ep[j * 3 + 2];
        float dx0 = ex - i0x, dy0 = ey - i0y, dz0 = ez - i0z;
        float dx1 = ex - i1x, dy1 = ey - i1y, dz1 = ez - i1z;
        float n0 = sqrtf(dx0 * dx0 + dy0 * dy0 + dz0 * dz0);
        float n1 = sqrtf(dx1 * dx1 + dy1 * dy1 + dz1 * dz1);
        float acc = bf_b[c];
        acc += dx0 * bf_w[0 * DP + c];
        acc += dy0 * bf_w[1 * DP + c];
        acc += dz0 * bf_w[2 * DP + c];
        acc += dx1 * bf_w[3 * DP + c];
        acc += dy1 * bf_w[4 * DP + c];
        acc += dz1 * bf_w[5 * DP + c];
        acc += n0 * bf_w[6 * DP + c];
        acc += n1 * bf_w[7 * DP + c];
        s1e[idx] = fast_tanh(acc);
    }
    // jastrow terms (combine's exact per-term math; summed e-major by t0 later)
    if (t < 2 * NELEC) {
        int e = t >> 1, ion = t & 1;
        const float* epb = elec_pos + b * NELEC * DIM;
        float ex = epb[e * 3 + 0], ey = epb[e * 3 + 1], ez = epb[e * 3 + 2];
        float ix = ion_pos[ion * 3 + 0], iy = ion_pos[ion * 3 + 1], iz = ion_pos[ion * 3 + 2];
        float dx = ex - ix, dy = ey - iy, dz = ez - iz;
        jterm[t] = jk[ion] * sqrtf(dx * dx + dy * dy + dz * dz);
    }
    __syncthreads();

    // ---- stage 2: G[j][i*64+c] = s1e[j][:] @ w0[s][32i:32i+32, c] ----
    // Slice-outer: this lane's w0 column for owned i-slice lives in wcol[32] (loaded
    // ONCE, reused across all 5 j). 96 global loads/wave vs R13's 480; MAC order per
    // G element identical (wcol[q*4+e] == old wb[e*NDENSE]) -> bit-identical output.
    const float* w0s = w0 + s * (NPER * DP) * NDENSE;   // [160][64]
    #pragma unroll
    for (int m = 0; m < 3; m++) {
        const int i = wave + 2 * m;         // wave0: i=0,2,4  wave1: i=1,3 (m=2 skipped)
        if (i < NPER) {                     // wave-uniform branch
            float wcol[DP];
            #pragma unroll
            for (int k = 0; k < DP; k++) wcol[k] = w0s[(i * DP + k) * NDENSE + lane];
            #pragma unroll
            for (int j = 0; j < NPER; j++) {
                float acc = 0.f;
                #pragma unroll
                for (int q = 0; q < 8; q++) {
                    float4 sv = *(const float4*)(s1e + j * DP + q * 4);   // LDS broadcast
                    acc += sv.x * wcol[q * 4 + 0];
                    acc += sv.y * wcol[q * 4 + 1];
                    acc += sv.z * wcol[q * 4 + 2];
                    acc += sv.w * wcol[q * 4 + 3];
                }
                GROW(j)[i * NDENSE + lane] = acc;
            }
        }
    }
    __syncthreads();

    const float* b0s = b0 + s * NDENSE;
    const float* w2s = w2 + s * NDENSE;     // w2 is [s][64][1]

    // ---- stage 3 phase 1: lane = perm. h_p built in registers (G still live) ----
    const int pid = wave * 60 + lane;
    float sign = 0.f;
    int p0 = 0, p1 = 0, p2 = 0, p3 = 0, p4 = 0;
    if (lane < 60) {
        int p = pid;
        unsigned el = 0x43210u;
        int d0 = p / 24; p -= d0 * 24;
        int d1 = p / 6;  p -= d1 * 6;
        int d2 = p / 2;  p -= d2 * 2;
        int d3 = p;
        p0 = pick_remove(el, d0);
        p1 = pick_remove(el, d1);
        p2 = pick_remove(el, d2);
        p3 = pick_remove(el, d3);
        p4 = el & 0xF;
        sign = ((d0 + d1 + d2 + d3) & 1) ? -1.f : 1.f;
    }
    const float* g0 = GROW(p0) + 0 * NDENSE;
    const float* g1 = GROW(p1) + 1 * NDENSE;
    const float* g2 = GROW(p2) + 2 * NDENSE;
    const float* g3 = GROW(p3) + 3 * NDENSE;
    const float* g4 = GROW(p4) + 4 * NDENSE;

    float h[NDENSE];                        // constant-indexed -> VGPR-resident
    float hdot = 0.f;
    #pragma unroll
    for (int cc = 0; cc < NDENSE / 4; cc++) {
        float4 a = *(const float4*)(b0s + cc * 4);                    // uniform -> s_load
        float4 q;
        q = *(const float4*)(g0 + cc * 4); a.x += q.x; a.y += q.y; a.z += q.z; a.w += q.w;
        q = *(const float4*)(g1 + cc * 4); a.x += q.x; a.y += q.y; a.z += q.z; a.w += q.w;
        q = *(const float4*)(g2 + cc * 4); a.x += q.x; a.y += q.y; a.z += q.z; a.w += q.w;
        q = *(const float4*)(g3 + cc * 4); a.x += q.x; a.y += q.y; a.z += q.z; a.w += q.w;
        q = *(const float4*)(g4 + cc * 4); a.x += q.x; a.y += q.y; a.z += q.z; a.w += q.w;
        float t0 = fast_tanh(a.x), t1 = fast_tanh(a.y), t2 = fast_tanh(a.z), t3 = fast_tanh(a.w);
        h[cc * 4 + 0] = t0; h[cc * 4 + 1] = t1; h[cc * 4 + 2] = t2; h[cc * 4 + 3] = t3;
        hdot += t0 * w2s[cc * 4 + 0] + t1 * w2s[cc * 4 + 1]
              + t2 * w2s[cc * 4 + 2] + t3 * w2s[cc * 4 + 3];
    }

    double dvh = (double)(sign * hdot);     // sign=0 for lanes 60-63
    #pragma unroll
    for (int off = 32; off > 0; off >>= 1) dvh += __shfl_down(dvh, off, 64);
    if (lane == 0) red_h[s][wave] = dvh;

    __syncthreads();                        // all G reads complete -> pool reusable

    // park h transposed: HT[k][pid] (b32 writes, consecutive pids -> 2 lanes/bank = free)
    if (lane < 60) {
        #pragma unroll
        for (int k = 0; k < NDENSE; k++) HTROW(k)[pid] = h[k];
    }
    __syncthreads();                        // HT visible

    // ---- stage 3 phase 2: 8x8 tile GEMM V[120x64] = H @ W1, packed-fp32 FMA (R12) ----
    const int pg = lane >> 3, jg = lane & 7;
    const int pb = wave ? (56 + 8 * pg) : (8 * pg);
    const float* w1s = w1 + s * NDENSE * NDENSE;
    const float* b1s = b1 + s * NDENSE;
    const float* wgp = w1s + 8 * jg;        // this lane's j-octet in w1 row k

    v2f vp[4][8];
    #pragma unroll
    for (int ip = 0; ip < 4; ip++)
        #pragma unroll
        for (int r = 0; r < 8; r++) vp[ip][r] = (v2f)(0.f);

    v4f ha_n = *(const v4f*)(&HTROW(0)[pb]);
    v4f hb_n = *(const v4f*)(&HTROW(0)[pb + 4]);
    v4f wa_n = *(const v4f*)(wgp);
    v4f wb_n = *(const v4f*)(wgp + 4);
    #pragma unroll 4
    for (int k = 0; k < NDENSE; k++) {
        const v4f ha = ha_n, hb = hb_n, wa = wa_n, wb = wb_n;
        if (k + 1 < NDENSE) {               // R10-validated k+1 prefetch
            ha_n = *(const v4f*)(&HTROW(k + 1)[pb]);
            hb_n = *(const v4f*)(&HTROW(k + 1)[pb + 4]);
            wa_n = *(const v4f*)(wgp + (k + 1) * NDENSE);
            wb_n = *(const v4f*)(wgp + (k + 1) * NDENSE + 4);
        }
        v2f hp[4] = {ha.xy, ha.zw, hb.xy, hb.zw};   // perm pairs
        v2f wp[4] = {wa.xy, wa.zw, wb.xy, wb.zw};   // j pairs
        #pragma unroll
        for (int ip = 0; ip < 4; ip++) {
            PK_FMA_LO(vp[ip][0], hp[ip], wp[0]);
            PK_FMA_HI(vp[ip][1], hp[ip], wp[0]);
            PK_FMA_LO(vp[ip][2], hp[ip], wp[1]);
            PK_FMA_HI(vp[ip][3], hp[ip], wp[1]);
            PK_FMA_LO(vp[ip][4], hp[ip], wp[2]);
            PK_FMA_HI(vp[ip][5], hp[ip], wp[2]);
            PK_FMA_LO(vp[ip][6], hp[ip], wp[3]);
            PK_FMA_HI(vp[ip][7], hp[ip], wp[3]);
        }
    }

    // epilogue: lanesum = sum_i sgn_i * sum_r tanh(v[i][r]+b1[j]) * w2[j]
    float4 b1a = *(const float4*)(b1s + 8 * jg);
    float4 b1b = *(const float4*)(b1s + 8 * jg + 4);
    float4 w2a = *(const float4*)(w2s + 8 * jg);
    float4 w2b = *(const float4*)(w2s + 8 * jg + 4);
    const float b1v[8] = {b1a.x, b1a.y, b1a.z, b1a.w, b1b.x, b1b.y, b1b.z, b1b.w};
    const float w2v[8] = {w2a.x, w2a.y, w2a.z, w2a.w, w2b.x, w2b.y, w2b.z, w2b.w};

    float lanesum = 0.f;
    #pragma unroll
    for (int i = 0; i < 8; i++) {
        int p = pb + i;                      // Lehmer parity
        int d0 = p / 24;  int r0 = p - 24 * d0;
        int d1 = r0 / 6;  int r1 = r0 - 6 * d1;
        int d2 = r1 >> 1; int d3 = r1 & 1;
        float sgn = ((d0 + d1 + d2 + d3) & 1) ? -1.f : 1.f;
        if (wave == 1 && pg == 0) sgn = 0.f; // duplicate tile (perms 56-63)
        float si = 0.f;
        #pragma unroll
        for (int r = 0; r < 8; r++) {
            float vir = (i & 1) ? vp[i >> 1][r].y : vp[i >> 1][r].x;
            si = fmaf(fast_tanh(vir + b1v[r]), w2v[r], si);
        }
        lanesum = fmaf(sgn, si, lanesum);
    }

    double dvj = (double)lanesum;
    #pragma unroll
    for (int off = 32; off > 0; off >>= 1) dvj += __shfl_down(dvj, off, 64);
    if (lane == 0) red_j[s][wave] = dvj;
    __syncthreads();

    // ---- inline combine (R13-validated) ----
    if (t == 0) {
        float ps0 = (float)((red_h[0][0] + red_h[0][1]) + (red_j[0][0] + red_j[0][1]));
        float ps1 = (float)((red_h[1][0] + red_h[1][1]) + (red_j[1][0] + red_j[1][1]));
        float jas = 0.f;
        #pragma unroll
        for (int i = 0; i < 2 * NELEC; i++) jas += jterm[i];
        out[b] = logf(fabsf(ps0 * ps1)) - jas;
    }
    // b2 omitted: sum_p sign_p = 0 kills it exactly.
}

extern "C" void kernel_launch(void* const* d_in, const int* in_sizes, int n_in,
                              void* d_out, int out_size, void* d_ws, size_t ws_size,
                              hipStream_t stream) {
    const float* elec_pos = (const float*)d_in[0];
    const float* ion_pos  = (const float*)d_in[1];
    const float* bf_w     = (const float*)d_in[2];
    const float* bf_b     = (const float*)d_in[3];
    const float* w0       = (const float*)d_in[4];
    const float* b0       = (const float*)d_in[5];
    const float* w1       = (const float*)d_in[6];
    const float* b1       = (const float*)d_in[7];
    const float* w2       = (const float*)d_in[8];
    const float* jk       = (const float*)d_in[10];
    float* out = (float*)d_out;

    const int B = in_sizes[0] / (NELEC * DIM);   // 2048

    hipLaunchKernelGGL(antisym_fused,
                       dim3(B), dim3(256), 0, stream,
                       elec_pos, ion_pos, bf_w, bf_b, w0, b0, w1, b1, w2, jk, out, B);
}